// Round 5
// baseline (198.503 us; speedup 1.0000x reference)
//
#include <hip/hip_runtime.h>
#include <cstdint>

typedef int v4i __attribute__((ext_vector_type(4)));

#define K_DIM 4096
#define BM 256
#define BN 256
#define BK 64
#define NT (K_DIM / BK)          // 64 K-tiles
#define TILE_BYTES (BM * BK)     // 16 KiB per operand tile
#define BUF_STRIDE (2 * TILE_BYTES)   // A tile + B tile = 32 KiB
#define NBUF 4                   // 128 KiB LDS, stage-ahead depth 3

// ---------------------------------------------------------------------------
// Kernel 0: pack int32 weight -> int8.
// ---------------------------------------------------------------------------
__global__ __launch_bounds__(256) void pack_weight(
    const int* __restrict__ w32, int8_t* __restrict__ w8, int total16)
{
    const int i = blockIdx.x * 256 + threadIdx.x;
    if (i >= total16) return;
    const v4i* src = reinterpret_cast<const v4i*>(w32) + i * 4;
    v4i out;
#pragma unroll
    for (int j = 0; j < 4; ++j) {
        const v4i v = src[j];
        out[j] = (v.x & 0xff) | ((v.y & 0xff) << 8) |
                 ((v.z & 0xff) << 16) | ((unsigned)(v.w & 0xff) << 24);
    }
    reinterpret_cast<v4i*>(w8)[i] = out;
}

// ---------------------------------------------------------------------------
// Kernel 1: per-row symmetric int8 quantization (verified).
// ---------------------------------------------------------------------------
__global__ __launch_bounds__(256) void quant_rows(
    const float* __restrict__ x, int8_t* __restrict__ q,
    float* __restrict__ scales)
{
    const int row = blockIdx.x;
    const int t   = threadIdx.x;
    const float4* xr4 = reinterpret_cast<const float4*>(x + (size_t)row * K_DIM);

    float4 v[4];
    float m = 0.0f;
#pragma unroll
    for (int i = 0; i < 4; ++i) {
        v[i] = xr4[i * 256 + t];
        m = fmaxf(m, fmaxf(fmaxf(fabsf(v[i].x), fabsf(v[i].y)),
                           fmaxf(fabsf(v[i].z), fabsf(v[i].w))));
    }
#pragma unroll
    for (int off = 32; off >= 1; off >>= 1)
        m = fmaxf(m, __shfl_xor(m, off, 64));

    __shared__ float wmax[4];
    if ((t & 63) == 0) wmax[t >> 6] = m;
    __syncthreads();
    const float am = fmaxf(fmaxf(wmax[0], wmax[1]), fmaxf(wmax[2], wmax[3]));
    const float s  = fmaxf(am / 127.0f, 1e-8f);
    if (t == 0) scales[row] = s;

    int* qi = reinterpret_cast<int*>(q + (size_t)row * K_DIM);
#pragma unroll
    for (int i = 0; i < 4; ++i) {
        const float e[4] = {v[i].x, v[i].y, v[i].z, v[i].w};
        unsigned packed = 0;
#pragma unroll
        for (int j = 0; j < 4; ++j) {
            float r = rintf(e[j] / s);
            r = fminf(fmaxf(r, -127.0f), 127.0f);
            packed |= ((unsigned)((int)r & 0xff)) << (8 * j);
        }
        qi[i * 256 + t] = (int)packed;
    }
}

// ---------------------------------------------------------------------------
// Kernel 2: int8 GEMM, 256x256 tile, BK=64, 8 waves (2Mx4N), NBUF=4 LDS,
// counted vmcnt(4) staging (stage tile t+3 during t), cross-phase pipelined
// COMPILER-SCHEDULED fragment reads (const-offset ds_read_b128, auto counted
// lgkmcnt), 2 barriers/tile, setprio around MFMA clusters.
//
// Race proof (unchanged from R3/R4, verified passing): entering tile t, tiles
// t,t+1 resident+visible; t+2's 4 loads in flight; t+3 staged during t into
// buf[(t+3)&3] whose previous readers (tile t-1) retired all reads before
// t-1's final barrier. Explicit lgkmcnt(8) before barrier#2 retires this
// tile's bufc reads (sA1) before any wave can begin next tile's STAGE_A into
// bufc's future alias; NA0/NB reads crossing barrier#2 target bufn, which is
// not overwritten until tile t+2's stages (>= one full barrier after their
// auto-wait retirement before t+1's MFMA_Q(0)).
// ---------------------------------------------------------------------------
__global__ __launch_bounds__(512, 2) void gemm_i8(
    const int8_t* __restrict__ A,   // [M][K] quantized activations
    const int8_t* __restrict__ B,   // [N][K] packed weight
    const float* __restrict__ sA,   // [M] per-row scales
    const float* __restrict__ wsc,  // [1] weight scale
    float* __restrict__ C,          // [M][N]
    int M, int N)
{
    __shared__ int8_t lds[NBUF * BUF_STRIDE];   // 128 KiB

    const int t    = threadIdx.x;
    const int lane = t & 63;
    const int w    = t >> 6;
    const int wr   = w >> 2;        // 0..1 -> 128-row half
    const int wc   = w & 3;         // 0..3 -> 64-col slice

    // T1: XCD-aware block swizzle (nwg = 512, divisible by 8)
    const int nwg = gridDim.x;
    int bid = blockIdx.x;
    if ((nwg & 7) == 0) bid = (bid & 7) * (nwg >> 3) + (bid >> 3);
    const int ntn  = N / BN;
    const int brow = (bid / ntn) * BM;
    const int bcol = (bid % ntn) * BN;

    // ---- staging: linear LDS dest, inverse-swizzled global src (verified) --
    const int idx0 = t;
    const int idx1 = t + 512;
    const int r0 = idx0 >> 2, r1 = idx1 >> 2;
    const int c0 = (((idx0 & 3) ^ ((r0 >> 1) & 3)) << 4);
    const int c1 = (((idx1 & 3) ^ ((r1 >> 1) & 3)) << 4);
    const int8_t* gA0 = A + (size_t)(brow + r0) * K_DIM + c0;
    const int8_t* gA1 = A + (size_t)(brow + r1) * K_DIM + c1;
    const int8_t* gB0 = B + (size_t)(bcol + r0) * K_DIM + c0;
    const int8_t* gB1 = B + (size_t)(bcol + r1) * K_DIM + c1;
    const int dst0 = idx0 * 16, dst1 = idx1 * 16;

#define GLDS(gp, off) \
    __builtin_amdgcn_global_load_lds( \
        (const __attribute__((address_space(1))) void*)(gp), \
        (__attribute__((address_space(3))) void*)(lds + (off)), 16, 0, 0)
#define STAGE_A(buf, tt) do { \
    GLDS(gA0 + (size_t)(tt) * BK, (buf) * BUF_STRIDE + dst0); \
    GLDS(gA1 + (size_t)(tt) * BK, (buf) * BUF_STRIDE + dst1); } while (0)
#define STAGE_B(buf, tt) do { \
    GLDS(gB0 + (size_t)(tt) * BK, (buf) * BUF_STRIDE + TILE_BYTES + dst0); \
    GLDS(gB1 + (size_t)(tt) * BK, (buf) * BUF_STRIDE + TILE_BYTES + dst1); } while (0)

    // ---- per-lane fragment base offsets; frag (mh,m): +mh*4096 + m*1024 ----
    // swz bits depend only on lane (16-row strides vanish mod the XOR field),
    // so all frag deltas are compile-time immediates for ds_read offset:.
    const int l15 = lane & 15;
    const unsigned swz = ((unsigned)((lane >> 4) ^ ((l15 >> 1) & 3))) << 4;
    const unsigned vA = (unsigned)((wr * 128 + l15) * BK) + swz;
    const unsigned vB = (unsigned)(TILE_BYTES + (wc * 64 + l15) * BK) + swz;

    v4i acc[8][4];
#pragma unroll
    for (int m = 0; m < 8; ++m)
#pragma unroll
        for (int n = 0; n < 4; ++n)
            acc[m][n] = (v4i){0, 0, 0, 0};

    v4i sA0a[4], sA0b[4], sBa[4], sBb[4], sA1[4];

    // ---- prologue: stage tiles 0,1,2; retire 0,1; pre-read tile 0 ----------
    STAGE_A(0, 0); STAGE_B(0, 0);
    STAGE_A(1, 1); STAGE_B(1, 1);
    STAGE_A(2, 2); STAGE_B(2, 2);
    asm volatile("s_waitcnt vmcnt(4)" ::: "memory");
    __builtin_amdgcn_s_barrier();
#pragma unroll
    for (int m = 0; m < 4; ++m) {
        sA0a[m] = *(const v4i*)(lds + vA + m * 1024);
        sBa[m]  = *(const v4i*)(lds + vB + m * 1024);
    }

#define MFMA_Q(BASE, AV, BV) do { \
    acc[BASE+0][0] = __builtin_amdgcn_mfma_i32_16x16x64_i8(AV[0], BV[0], acc[BASE+0][0], 0,0,0); \
    acc[BASE+0][1] = __builtin_amdgcn_mfma_i32_16x16x64_i8(AV[0], BV[1], acc[BASE+0][1], 0,0,0); \
    acc[BASE+0][2] = __builtin_amdgcn_mfma_i32_16x16x64_i8(AV[0], BV[2], acc[BASE+0][2], 0,0,0); \
    acc[BASE+0][3] = __builtin_amdgcn_mfma_i32_16x16x64_i8(AV[0], BV[3], acc[BASE+0][3], 0,0,0); \
    acc[BASE+1][0] = __builtin_amdgcn_mfma_i32_16x16x64_i8(AV[1], BV[0], acc[BASE+1][0], 0,0,0); \
    acc[BASE+1][1] = __builtin_amdgcn_mfma_i32_16x16x64_i8(AV[1], BV[1], acc[BASE+1][1], 0,0,0); \
    acc[BASE+1][2] = __builtin_amdgcn_mfma_i32_16x16x64_i8(AV[1], BV[2], acc[BASE+1][2], 0,0,0); \
    acc[BASE+1][3] = __builtin_amdgcn_mfma_i32_16x16x64_i8(AV[1], BV[3], acc[BASE+1][3], 0,0,0); \
    acc[BASE+2][0] = __builtin_amdgcn_mfma_i32_16x16x64_i8(AV[2], BV[0], acc[BASE+2][0], 0,0,0); \
    acc[BASE+2][1] = __builtin_amdgcn_mfma_i32_16x16x64_i8(AV[2], BV[1], acc[BASE+2][1], 0,0,0); \
    acc[BASE+2][2] = __builtin_amdgcn_mfma_i32_16x16x64_i8(AV[2], BV[2], acc[BASE+2][2], 0,0,0); \
    acc[BASE+2][3] = __builtin_amdgcn_mfma_i32_16x16x64_i8(AV[2], BV[3], acc[BASE+2][3], 0,0,0); \
    acc[BASE+3][0] = __builtin_amdgcn_mfma_i32_16x16x64_i8(AV[3], BV[0], acc[BASE+3][0], 0,0,0); \
    acc[BASE+3][1] = __builtin_amdgcn_mfma_i32_16x16x64_i8(AV[3], BV[1], acc[BASE+3][1], 0,0,0); \
    acc[BASE+3][2] = __builtin_amdgcn_mfma_i32_16x16x64_i8(AV[3], BV[2], acc[BASE+3][2], 0,0,0); \
    acc[BASE+3][3] = __builtin_amdgcn_mfma_i32_16x16x64_i8(AV[3], BV[3], acc[BASE+3][3], 0,0,0); \
    } while (0)

    // CA0/CB: this tile's mh0 + B frags (read during prev tile's ph1).
    // NA0/NB: next tile's mh0 + B frags (read this tile's ph1).
#define TILE_BODY(T, CA0, CB, NA0, NB) do { \
    const int8_t* bufc_ = lds + cur * BUF_STRIDE; \
    const int8_t* bufn_ = lds + ((cur + 1) & 3) * BUF_STRIDE; \
    const int nx3 = (cur + 3) & 3; \
    /* ---- phase 0: read own mh1 frags, stage A(t+3), barrier, MFMA ---- */ \
    sA1[0] = *(const v4i*)(bufc_ + vA + 4096); \
    sA1[1] = *(const v4i*)(bufc_ + vA + 5120); \
    sA1[2] = *(const v4i*)(bufc_ + vA + 6144); \
    sA1[3] = *(const v4i*)(bufc_ + vA + 7168); \
    if ((T) + 3 < NT) STAGE_A(nx3, (T) + 3); \
    __builtin_amdgcn_s_barrier(); \
    __builtin_amdgcn_s_setprio(1); \
    MFMA_Q(0, CA0, CB); \
    __builtin_amdgcn_s_setprio(0); \
    /* ---- phase 1: read next tile's mh0+B, stage B(t+3), sync, MFMA -- */ \
    if ((T) + 1 < NT) { \
        NA0[0] = *(const v4i*)(bufn_ + vA);        \
        NA0[1] = *(const v4i*)(bufn_ + vA + 1024); \
        NA0[2] = *(const v4i*)(bufn_ + vA + 2048); \
        NA0[3] = *(const v4i*)(bufn_ + vA + 3072); \
        NB[0]  = *(const v4i*)(bufn_ + vB);        \
        NB[1]  = *(const v4i*)(bufn_ + vB + 1024); \
        NB[2]  = *(const v4i*)(bufn_ + vB + 2048); \
        NB[3]  = *(const v4i*)(bufn_ + vB + 3072); \
    } \
    if ((T) + 3 < NT) STAGE_B(nx3, (T) + 3); \
    if ((T) + 1 < NT) { \
        /* retire this tile's bufc reads before any wave can overwrite */ \
        asm volatile("s_waitcnt lgkmcnt(8)" ::: "memory"); \
        __builtin_amdgcn_sched_barrier(0); \
        if ((T) + 3 < NT) asm volatile("s_waitcnt vmcnt(4)" ::: "memory"); \
        else              asm volatile("s_waitcnt vmcnt(0)" ::: "memory"); \
        __builtin_amdgcn_s_barrier(); \
    } \
    __builtin_amdgcn_s_setprio(1); \
    MFMA_Q(4, sA1, CB); \
    __builtin_amdgcn_s_setprio(0); \
    cur = (cur + 1) & 3; \
    } while (0)

    int cur = 0;
    for (int tt = 0; tt < NT; tt += 2) {
        TILE_BODY(tt,     sA0a, sBa, sA0b, sBb);
        TILE_BODY(tt + 1, sA0b, sBb, sA0a, sBa);
    }

    // ---- epilogue: C/D layout col = lane&15, row = (lane>>4)*4 + reg ------
    const float wsv = wsc[0];
#pragma unroll
    for (int m = 0; m < 8; ++m) {
        const int rbase = brow + wr * 128 + m * 16 + (lane >> 4) * 4;
        float sc[4];
#pragma unroll
        for (int j = 0; j < 4; ++j) sc[j] = sA[rbase + j] * wsv;
#pragma unroll
        for (int n = 0; n < 4; ++n) {
            const int col = bcol + wc * 64 + n * 16 + (lane & 15);
#pragma unroll
            for (int j = 0; j < 4; ++j)
                C[(size_t)(rbase + j) * N + col] = (float)acc[m][n][j] * sc[j];
        }
    }
#undef GLDS
#undef STAGE_A
#undef STAGE_B
#undef MFMA_Q
#undef TILE_BODY
}

extern "C" void kernel_launch(void* const* d_in, const int* in_sizes, int n_in,
                              void* d_out, int out_size, void* d_ws, size_t ws_size,
                              hipStream_t stream) {
    const float* x      = (const float*)d_in[0];
    const int*   w32    = (const int*)d_in[1];     // int8 widened to int32
    const float* wscale = (const float*)d_in[2];
    float*       out    = (float*)d_out;

    const int M = in_sizes[0] / K_DIM;   // 8192
    const int N = in_sizes[1] / K_DIM;   // 4096

    int8_t* q      = (int8_t*)d_ws;
    float*  scales = (float*)((char*)d_ws + (size_t)M * K_DIM);
    int8_t* w8     = (int8_t*)((char*)d_ws + (size_t)M * K_DIM + (size_t)M * sizeof(float));

    const int total16 = (N * K_DIM) / 16;
    pack_weight<<<(total16 + 255) / 256, 256, 0, stream>>>(w32, w8, total16);

    quant_rows<<<M, 256, 0, stream>>>(x, q, scales);

    const int nblk = (M / BM) * (N / BN);   // 512
    gemm_i8<<<nblk, 512, 0, stream>>>(q, w8, scales, wscale, out, M, N);
}